// Round 6
// baseline (127.815 us; speedup 1.0000x reference)
//
#include <hip/hip_runtime.h>
#include <hip/hip_fp16.h>

// PairwiseScore: B=2, N=256, E=512, H=150 (padded to 160)
// out[b,i,j] = (m[b,i] + m[b,j] + MLP3(g_i, g_j)) / 3
//
// R9: BUILDER DELETED via algebra + fp16.
//   D1[h][j] = W1c^T (g_i . g_j) + W1b^T g_j + W1a^T g_i + b1
//              \__ GEMM1, A static _/   \_ HJ table _/  \_ HI table _/
//   - A-operand (W1cF frags) is STATIC: DMA'd to LDS via global_load_lds
//     (double-buffered 2x40KB megas, no VALU, no reg round-trip).
//   - B-operand built in regs: g_j frag (global, already needed) * g_i slice
//     (LDS broadcast) with v_pk_mul_f16 -- 8 VALU per k-tile per wave.
//   - HI/HJ = tiny global GEMMs done once in prep_hij (32 blocks, MFMA).
//   - R0's 16us of builder VALU + 10240 LDS writes + 2 build barriers GONE;
//     6 barriers total.
// Evidence driving this: R0/R7/R8 all ~17-19% MfmaUtil, 25-30% VALUBusy at
// 20/20/40% occupancy -- barrier-lockstep serial phases, builder = top pipe.
// fp16 (not bf16): native v_pk_mul_f16 for the elementwise product, finer
// mantissa (tolerance-safe; exponent range fine for ~N(0,1) data).

typedef __attribute__((ext_vector_type(4))) float f32x4;
typedef __attribute__((ext_vector_type(4))) unsigned int u32x4;
typedef __attribute__((ext_vector_type(2))) unsigned int u32x2;
typedef __attribute__((ext_vector_type(8))) _Float16 f16x8;
typedef __attribute__((ext_vector_type(2))) _Float16 f16x2;

#define NN 256
#define NE 512
#define NH 150
#define HP 160      // padded H
#define NKT 16      // NE/32 k-tiles for GEMM1
#define NHT 10      // HP/16 h-tiles
#define NS 5        // HP/32 k-steps for GEMM2

// ---------- helpers ----------
__device__ __forceinline__ unsigned pk_f16(float a, float b) {
  return __builtin_bit_cast(unsigned, __builtin_amdgcn_cvt_pkrtz(a, b));
}
__device__ __forceinline__ f16x8 prod8(u32x4 a, u32x4 b) {
  u32x4 p;
#pragma unroll
  for (int q = 0; q < 4; ++q) {
    f16x2 x = __builtin_bit_cast(f16x2, a[q]);
    f16x2 y = __builtin_bit_cast(f16x2, b[q]);
    p[q] = __builtin_bit_cast(unsigned, (f16x2)(x * y));
  }
  return __builtin_bit_cast(f16x8, p);
}
__device__ __forceinline__ void async_cp16(const unsigned* gsrc, unsigned* ldst) {
  __builtin_amdgcn_global_load_lds(
      (const __attribute__((address_space(1))) unsigned*)gsrc,
      (__attribute__((address_space(3))) unsigned*)ldst, 16, 0, 0);
}

// ---------- prep: grid 365 x 256 (R7 shape, fp16 pack) ----------
//  bid [0,256)   : g (f32) -> g_f16
//  bid [256,352) : W1a/b/c -> WaF/WbF/WcF frag-major via half-tile transpose
//  bid [352,365) : W2^T -> W2TF frag-major
__global__ __launch_bounds__(256) void prep_pack(
    const float* __restrict__ g, const float* __restrict__ W1,
    const float* __restrict__ W2,
    unsigned short* __restrict__ g_f16, unsigned short* __restrict__ WaF,
    unsigned short* __restrict__ WbF, unsigned short* __restrict__ WcF,
    unsigned short* __restrict__ W2TF)
{
  __shared__ float tile[16][161];
  int bid = blockIdx.x, tid = threadIdx.x;
  if (bid < 256) {
    int t = bid * 256 + tid;
    f32x4 v = ((const f32x4*)g)[t];
    u32x2 o; o[0] = pk_f16(v[0], v[1]); o[1] = pk_f16(v[2], v[3]);
    ((u32x2*)g_f16)[t] = o;
  } else if (bid < 352) {
    int bb = bid - 256;
    int mat = bb >> 5;
    int kt = (bb & 31) >> 1;
    int half = bb & 1;
    const float* __restrict__ Wm =
        W1 + ((size_t)mat * NE + (size_t)kt * 32 + (size_t)half * 16) * NH;
    for (int idx = tid; idx < 16 * NH; idx += 256) {
      int e = idx / NH, h = idx - e * NH;
      tile[e][h] = Wm[idx];
    }
    for (int idx = tid; idx < 16 * 10; idx += 256)
      tile[idx / 10][NH + (idx % 10)] = 0.f;
    __syncthreads();
    unsigned short* dst = (mat == 0) ? WaF : (mat == 1) ? WbF : WcF;
#pragma unroll
    for (int r = 0; r < 2; ++r) {
      int rr = tid + r * 256;
      if (rr < 320) {
        int chh = rr >> 5;
        int l = half * 32 + (rr & 31);
        int el = ((l >> 4) & 1) * 8;
        int h = chh * 16 + (l & 15);
        u32x4 o;
#pragma unroll
        for (int q = 0; q < 4; ++q)
          o[q] = pk_f16(tile[el + 2 * q][h], tile[el + 2 * q + 1][h]);
        ((u32x4*)dst)[kt * 640 + chh * 64 + l] = o;
      }
    }
  } else {
    int row = (bid - 352) * 256 + tid;
    if (row < 3200) {
      int s = row / 640; int rem = row - s * 640;
      int l = rem & 63; int chh = rem >> 6;
      int k = s * 32 + (l >> 4) * 8;
      int hp = chh * 16 + (l & 15);
      u32x4 o;
#pragma unroll
      for (int q = 0; q < 4; ++q) {
        int k0 = k + 2 * q, k1 = k0 + 1;
        float v0 = (k0 < NH && hp < NH) ? W2[(size_t)k0 * NH + hp] : 0.f;
        float v1 = (k1 < NH && hp < NH) ? W2[(size_t)k1 * NH + hp] : 0.f;
        o[q] = pk_f16(v0, v1);
      }
      ((u32x4*)W2TF)[row] = o;
    }
  }
}

// ---------- prep_hij: HI[b,n,h]=sum_e g W1a ; HJ=sum_e g W1b ----------
// 32 blocks x 256 thr: block=(b, 16-row chunk); wave=(mat, ht-half).
__global__ __launch_bounds__(256) void prep_hij(
    const unsigned short* __restrict__ g_f16,
    const unsigned short* __restrict__ WaF,
    const unsigned short* __restrict__ WbF,
    float* __restrict__ HI, float* __restrict__ HJ)
{
  const int bid = blockIdx.x, tid = threadIdx.x;
  const int b = bid >> 4, nt = bid & 15;
  const int lane = tid & 63, wave = tid >> 6;
  const int c16 = lane & 15, quad = lane >> 4;
  const int mat = wave & 1, hh = wave >> 1;
  const u32x4* AF = (const u32x4*)(mat ? WbF : WaF);
  float* T = mat ? HJ : HI;
  const int n = nt * 16 + c16;
  const u32x4* gB = (const u32x4*)g_f16;
  const size_t gidx = (size_t)(b * NN + n) * 64 + quad;

  f32x4 acc[5] = {};
#pragma unroll
  for (int kt = 0; kt < NKT; ++kt) {
    f16x8 bf = __builtin_bit_cast(f16x8, gB[gidx + (size_t)kt * 4]);
#pragma unroll
    for (int t = 0; t < 5; ++t) {
      f16x8 af = __builtin_bit_cast(f16x8, AF[(kt * NHT + hh * 5 + t) * 64 + lane]);
      acc[t] = __builtin_amdgcn_mfma_f32_16x16x32_f16(af, bf, acc[t], 0, 0, 0);
    }
  }
#pragma unroll
  for (int t = 0; t < 5; ++t)
    *(f32x4*)(T + (size_t)(b * NN + n) * HP + (hh * 5 + t) * 16 + quad * 4) = acc[t];
}

// ---------- main kernel: 512 threads, one block per (b,i) ----------
__global__ __launch_bounds__(512) void pair_main(
    const float* __restrict__ mention, const float* __restrict__ b1,
    const float* __restrict__ b2, const float* __restrict__ W3,
    const float* __restrict__ b3,
    const unsigned short* __restrict__ g_f16,
    const unsigned short* __restrict__ W1cF,
    const unsigned short* __restrict__ W2TF,
    const float* __restrict__ HI, const float* __restrict__ HJ,
    float* __restrict__ out)
{
  __shared__ u32x4 stage[5120];             // 80 KB: 2x40KB W1cF megas / W2TF
  __shared__ unsigned int gi_lds[NE / 2];   // g_i fp16 (1 KB)
  __shared__ alignas(16) float bias1[HP];   // b1 + HI[i]
  __shared__ alignas(16) float bias2[HP];
  __shared__ alignas(16) float w3s[HP];

  const int tid = threadIdx.x;
  const int bi = blockIdx.x;
  const int b = bi >> 8, i = bi & 255;
  const int lane = tid & 63, wave = tid >> 6;   // 8 waves
  const int c16 = lane & 15, quad = lane >> 4;

  // ---- phase 0: per-block constants ----
  if (tid < 64) {
    const u32x4* grow = (const u32x4*)(g_f16 + (size_t)(b * NN + i) * NE);
    ((u32x4*)gi_lds)[tid] = grow[tid];
  } else if (tid >= 64 && tid < 64 + HP) {
    int h = tid - 64;
    bias1[h] = ((h < NH) ? b1[h] : 0.f) + HI[(size_t)(b * NN + i) * HP + h];
  } else if (tid >= 256 && tid < 256 + HP) {
    int h = tid - 256;
    bias2[h] = (h < NH) ? b2[h] : 0.f;
    w3s[h]   = (h < NH) ? W3[h] : 0.f;
  }

  // ---- DMA stager: mega m = 4 k-tiles of W1cF (40KB) into buf (m&1) ----
  auto stage_mega = [&](int m) {
    const unsigned* src = (const unsigned*)W1cF + (size_t)m * 2560 * 4;
    unsigned* dstb = (unsigned*)(stage + (m & 1) * 2560);
#pragma unroll
    for (int r = 0; r < 5; ++r) {
      int idx = tid + r * 512;               // 0..2559
      async_cp16(src + (size_t)idx * 4, dstb + idx * 4);
    }
  };

  f32x4 acc1[NHT][2] = {};
  const u32x4* gB = (const u32x4*)g_f16;
  const u32x4* giq = (const u32x4*)gi_lds;
  const size_t gidx0 = (size_t)(b * NN + wave * 32 + c16) * 64 + quad;

  // ---- GEMM1 mega: A (static W1c^T) from LDS, B = g_i . g_j built in regs ----
  auto gemm1_mega = [&](int m) {
    const u32x4* As = stage + (m & 1) * 2560;
#pragma unroll
    for (int ktl = 0; ktl < 4; ++ktl) {
      int ktg = m * 4 + ktl;
      u32x4 gi4 = giq[ktg * 4 + quad];                       // broadcast slice
      u32x4 gj0 = gB[gidx0 + (size_t)ktg * 4];
      u32x4 gj1 = gB[gidx0 + 16 * 64 + (size_t)ktg * 4];
      f16x8 bf0 = prod8(gj0, gi4);
      f16x8 bf1 = prod8(gj1, gi4);
#pragma unroll
      for (int ht = 0; ht < NHT; ++ht) {
        f16x8 af = __builtin_bit_cast(f16x8, As[ktl * 640 + ht * 64 + lane]);
        acc1[ht][0] = __builtin_amdgcn_mfma_f32_16x16x32_f16(af, bf0, acc1[ht][0], 0, 0, 0);
        acc1[ht][1] = __builtin_amdgcn_mfma_f32_16x16x32_f16(af, bf1, acc1[ht][1], 0, 0, 0);
      }
    }
  };

  stage_mega(0);
  stage_mega(1);
  __syncthreads();   // B0: megas 0,1 + phase-0 LDS ready
  gemm1_mega(0);
  __syncthreads();   // B1: buf0 reads done
  stage_mega(2);     // DMA overlaps compute of mega 1
  gemm1_mega(1);
  __syncthreads();   // B2: mega-2 ready, buf1 reads done
  stage_mega(3);     // DMA overlaps compute of mega 2
  gemm1_mega(2);
  __syncthreads();   // B3: mega-3 ready
  gemm1_mega(3);
  __syncthreads();   // B4: all stage reads done -> free for W2TF

  // ---- stage W2^T (50KB) async; overlap epilogue-1 ----
#pragma unroll
  for (int r = 0; r < 7; ++r) {
    int row = tid + r * 512;
    if (row < 3200)
      async_cp16((const unsigned*)W2TF + (size_t)row * 4, (unsigned*)stage + row * 4);
  }

  // ---- epilogue 1: h1 = relu(D1 + bias1 + HJ[j]) -> fp16 in registers ----
  unsigned Hlo[NHT][2], Hhi[NHT][2];
#pragma unroll
  for (int ht = 0; ht < NHT; ++ht) {
    f32x4 bv = *(const f32x4*)(bias1 + ht * 16 + quad * 4);
#pragma unroll
    for (int jt = 0; jt < 2; ++jt) {
      int j = wave * 32 + jt * 16 + c16;
      f32x4 hj = *(const f32x4*)(HJ + (size_t)(b * NN + j) * HP + ht * 16 + quad * 4);
      f32x4 v = acc1[ht][jt];
      float r0 = fmaxf(v[0] + bv[0] + hj[0], 0.f);
      float r1 = fmaxf(v[1] + bv[1] + hj[1], 0.f);
      float r2 = fmaxf(v[2] + bv[2] + hj[2], 0.f);
      float r3 = fmaxf(v[3] + bv[3] + hj[3], 0.f);
      Hlo[ht][jt] = pk_f16(r0, r1);
      Hhi[ht][jt] = pk_f16(r2, r3);
    }
  }
  __syncthreads();       // B5: W2TF staged

  // ---- phase 2: D2 = W2^T h1 ; h1 C-layout -> B-frag via shfl (R0 verbatim) ----
  f32x4 acc2[NHT][2] = {};
  const int lA = ((lane >> 4) & 1) * 32 + c16;
  const int lB = lA + 16;
  const bool selHi = ((lane >> 5) & 1) != 0;

#pragma unroll
  for (int s = 0; s < NS; ++s) {
    f16x8 b2f[2];
#pragma unroll
    for (int jt = 0; jt < 2; ++jt) {
      unsigned a0 = (unsigned)__shfl((int)Hlo[2 * s][jt], lA);
      unsigned a1 = (unsigned)__shfl((int)Hhi[2 * s][jt], lA);
      unsigned a2 = (unsigned)__shfl((int)Hlo[2 * s][jt], lB);
      unsigned a3 = (unsigned)__shfl((int)Hhi[2 * s][jt], lB);
      unsigned d0 = (unsigned)__shfl((int)Hlo[2 * s + 1][jt], lA);
      unsigned d1 = (unsigned)__shfl((int)Hhi[2 * s + 1][jt], lA);
      unsigned d2 = (unsigned)__shfl((int)Hlo[2 * s + 1][jt], lB);
      unsigned d3 = (unsigned)__shfl((int)Hhi[2 * s + 1][jt], lB);
      u32x4 fr;
      fr[0] = selHi ? d0 : a0;
      fr[1] = selHi ? d1 : a1;
      fr[2] = selHi ? d2 : a2;
      fr[3] = selHi ? d3 : a3;
      b2f[jt] = __builtin_bit_cast(f16x8, fr);
    }
    const u32x4* A2 = stage + s * (NHT * 64);
#pragma unroll
    for (int ht = 0; ht < NHT; ++ht) {
      f16x8 af = __builtin_bit_cast(f16x8, A2[ht * 64 + lane]);
      acc2[ht][0] = __builtin_amdgcn_mfma_f32_16x16x32_f16(af, b2f[0], acc2[ht][0], 0, 0, 0);
      acc2[ht][1] = __builtin_amdgcn_mfma_f32_16x16x32_f16(af, b2f[1], acc2[ht][1], 0, 0, 0);
    }
  }

  // ---- epilogue 2 + GEMM3 ----
  float part0 = 0.f, part1 = 0.f;
#pragma unroll
  for (int ht = 0; ht < NHT; ++ht) {
    f32x4 bv = *(const f32x4*)(bias2 + ht * 16 + quad * 4);
    f32x4 wv = *(const f32x4*)(w3s + ht * 16 + quad * 4);
    f32x4 v0 = acc2[ht][0], v1 = acc2[ht][1];
#pragma unroll
    for (int r = 0; r < 4; ++r) {
      part0 += fmaxf(v0[r] + bv[r], 0.f) * wv[r];
      part1 += fmaxf(v1[r] + bv[r], 0.f) * wv[r];
    }
  }
  part0 += __shfl_xor(part0, 16); part0 += __shfl_xor(part0, 32);
  part1 += __shfl_xor(part1, 16); part1 += __shfl_xor(part1, 32);

  const float mi = mention[b * NN + i];
  const float b3v = b3[0];
  float sc = (quad == 0) ? part0 : part1;
  if (quad < 2) {
    int j = wave * 32 + quad * 16 + c16;
    float mj = mention[b * NN + j];
    out[((size_t)(b * NN + i)) * NN + j] = (mi + mj + sc + b3v) * (1.f / 3.f);
  }
}

// ---------- launch ----------
extern "C" void kernel_launch(void* const* d_in, const int* in_sizes, int n_in,
                              void* d_out, int out_size, void* d_ws, size_t ws_size,
                              hipStream_t stream) {
  const float* g  = (const float*)d_in[0];
  const float* m  = (const float*)d_in[1];
  const float* W1 = (const float*)d_in[2];
  const float* b1 = (const float*)d_in[3];
  const float* W2 = (const float*)d_in[4];
  const float* b2 = (const float*)d_in[5];
  const float* W3 = (const float*)d_in[6];
  const float* b3 = (const float*)d_in[7];
  float* out = (float*)d_out;

  char* ws = (char*)d_ws;
  unsigned short* g_f16 = (unsigned short*)(ws);               // 524288 B
  unsigned short* WaF   = (unsigned short*)(ws + 524288);      // 163840 B
  unsigned short* WbF   = (unsigned short*)(ws + 688128);      // 163840 B
  unsigned short* WcF   = (unsigned short*)(ws + 851968);      // 163840 B
  unsigned short* W2TF  = (unsigned short*)(ws + 1015808);     //  51200 B
  float*          HI    = (float*)(ws + 1067008);              // 327680 B
  float*          HJ    = (float*)(ws + 1394688);              // 327680 B -> 1.72MB

  prep_pack<<<365, 256, 0, stream>>>(g, W1, W2, g_f16, WaF, WbF, WcF, W2TF);
  prep_hij<<<32, 256, 0, stream>>>(g_f16, WaF, WbF, HI, HJ);
  pair_main<<<512, 512, 0, stream>>>(m, b1, b2, W3, b3, g_f16, WcF, W2TF,
                                     HI, HJ, out);
}